// Round 1
// baseline (320.012 us; speedup 1.0000x reference)
//
#include <hip/hip_runtime.h>

// Hierarchical smoothed-CE loss:
//   order:    CE over row[0:64],              target o = c2o[c],   eps=0.1
//   family:   CE over row[64+o*8 : +8],       target f%8,          eps=0.1
//   category: CE over row[576+f*32 : +32],    target c%32,         eps=0.1
// loss = mean_b(order + family + category)

constexpr int N_LOGITS = 16960;
constexpr int BATCH = 4096;
constexpr int WAVES_PER_BLOCK = 4;                 // 256 threads
constexpr int NBLOCKS = BATCH / WAVES_PER_BLOCK;   // 1024

__global__ __launch_bounds__(256) void hespias_partial(
    const float* __restrict__ pred,
    const int*   __restrict__ tgt,
    const int*   __restrict__ c2o,
    const int*   __restrict__ c2f,
    const int*   __restrict__ fam_start,
    const int*   __restrict__ fam_index,
    const int*   __restrict__ cat_start,
    const int*   __restrict__ cat_index,
    float*       __restrict__ ws)
{
    const int lane = threadIdx.x & 63;
    const int wid  = threadIdx.x >> 6;
    const int sample = blockIdx.x * WAVES_PER_BLOCK + wid;

    const float* __restrict__ row = pred + (size_t)sample * N_LOGITS;

    const int c  = tgt[sample];
    const int o  = c2o[c];
    const int f  = c2f[c];
    const int fs = fam_start[o];
    const int ft = fam_index[f];
    const int cs = cat_start[f];
    const int ct = cat_index[c];

    float loss = 0.0f;

    // ---------------- order: 64 logits, one per lane ----------------
    {
        float x = row[lane];
        float s = x, m = x;
        #pragma unroll
        for (int off = 32; off; off >>= 1) {
            s += __shfl_xor(s, off);
            m  = fmaxf(m, __shfl_xor(m, off));
        }
        float e = expf(x - m);
        #pragma unroll
        for (int off = 32; off; off >>= 1) e += __shfl_xor(e, off);
        float lse = m + logf(e);
        float xt  = __shfl(x, o);
        loss += lse - (0.9f * xt + 0.1f * (s * (1.0f / 64.0f)));
    }

    // ---------------- family: 8 logits, replicated 8x across wave ----
    {
        float x = row[fs + (lane & 7)];
        float s = x, m = x;
        #pragma unroll
        for (int off = 4; off; off >>= 1) {
            s += __shfl_xor(s, off);
            m  = fmaxf(m, __shfl_xor(m, off));
        }
        float e = expf(x - m);
        #pragma unroll
        for (int off = 4; off; off >>= 1) e += __shfl_xor(e, off);
        float lse = m + logf(e);
        float xt  = __shfl(x, ft);   // all 8-groups identical; group 0 lane ft
        loss += lse - (0.9f * xt + 0.1f * (s * (1.0f / 8.0f)));
    }

    // ---------------- category: 32 logits, replicated 2x -------------
    {
        float x = row[cs + (lane & 31)];
        float s = x, m = x;
        #pragma unroll
        for (int off = 16; off; off >>= 1) {
            s += __shfl_xor(s, off);
            m  = fmaxf(m, __shfl_xor(m, off));
        }
        float e = expf(x - m);
        #pragma unroll
        for (int off = 16; off; off >>= 1) e += __shfl_xor(e, off);
        float lse = m + logf(e);
        float xt  = __shfl(x, ct);
        loss += lse - (0.9f * xt + 0.1f * (s * (1.0f / 32.0f)));
    }

    // ---------------- per-block partial sum ---------------------------
    __shared__ float wsum[WAVES_PER_BLOCK];
    if (lane == 0) wsum[wid] = loss;
    __syncthreads();
    if (threadIdx.x == 0) {
        float t = 0.0f;
        #pragma unroll
        for (int i = 0; i < WAVES_PER_BLOCK; ++i) t += wsum[i];
        ws[blockIdx.x] = t;
    }
}

__global__ __launch_bounds__(1024) void hespias_final(
    const float* __restrict__ ws, float* __restrict__ out)
{
    float v = ws[threadIdx.x];                 // 1024 partials, 1024 threads
    #pragma unroll
    for (int off = 32; off; off >>= 1) v += __shfl_xor(v, off);
    __shared__ float sm[16];
    if ((threadIdx.x & 63) == 0) sm[threadIdx.x >> 6] = v;
    __syncthreads();
    if (threadIdx.x == 0) {
        float t = 0.0f;
        #pragma unroll
        for (int i = 0; i < 16; ++i) t += sm[i];
        out[0] = t * (1.0f / (float)BATCH);
    }
}

extern "C" void kernel_launch(void* const* d_in, const int* in_sizes, int n_in,
                              void* d_out, int out_size, void* d_ws, size_t ws_size,
                              hipStream_t stream) {
    const float* pred      = (const float*)d_in[0];
    const int*   tgt       = (const int*)  d_in[1];
    const int*   c2o       = (const int*)  d_in[2];
    const int*   c2f       = (const int*)  d_in[3];
    const int*   fam_start = (const int*)  d_in[4];
    // d_in[5] = family_end (unused: segments are always full length 8)
    const int*   fam_index = (const int*)  d_in[6];
    const int*   cat_start = (const int*)  d_in[7];
    // d_in[8] = category_end (unused: always full length 32)
    const int*   cat_index = (const int*)  d_in[9];
    float*       out       = (float*)d_out;
    float*       ws        = (float*)d_ws;

    hipLaunchKernelGGL(hespias_partial, dim3(NBLOCKS), dim3(256), 0, stream,
                       pred, tgt, c2o, c2f, fam_start, fam_index, cat_start,
                       cat_index, ws);
    hipLaunchKernelGGL(hespias_final, dim3(1), dim3(1024), 0, stream, ws, out);
}